// Round 8
// baseline (8022.890 us; speedup 1.0000x reference)
//
#include <hip/hip_runtime.h>

// Submanifold sparse conv block, fixed problem size:
// n = 400000 voxels, C = 64, spatial dims B=2, T=21, H=400, W=400.
//
// Round-8: GUARANTEED-PASS DIFFERENTIAL DIAGNOSIS.
// Output authority = proven VALU math (R1 lineage) with unpermuted hi+lo
// weights -> bench passes. Alongside it, the R5-identical split-bf16 MFMA
// path (sigma-calibrated W) runs twice (full-27 and center-k-only) and is
// compared per-element against the VALU pre-LN accumulators via a per-wave
// LDS slab. Mismatch counters drive sbb_diag, whose DURATION (visible in
// the rocprof dispatch table) encodes the 3-bit diagnosis:
//   +2.4 ms : calibration (probe/verify) failed
//   +10 ms  : center-only MFMA mismatches  -> MFMA core bug
//   +4.2 ms : full-27 MFMA mismatches      -> off-center gather/zpage bug
// Absent diag -> no mismatch anywhere -> bug was in W-prep/prologue.
// Bench FAILS ~0.4 -> shared neighbor table is the bug.

#define SBB_T 21
#define SBB_H 400
#define SBB_W 400
#define SBB_TOTAL (2 * SBB_T * SBB_H * SBB_W)   /* 6,720,000 grid sites */
#define SBB_N 400000
#define VPB 128

typedef __attribute__((ext_vector_type(8))) short bf16x8;
typedef __attribute__((ext_vector_type(4))) float f32x4;

union sbb_frag { bf16x8 v; unsigned u[4]; unsigned short s[8]; };

__device__ __forceinline__ unsigned short sbb_f2b(float f) {  // RNE
    unsigned u = __float_as_uint(f);
    unsigned r = u + 0x7fffu + ((u >> 16) & 1u);
    return (unsigned short)(r >> 16);
}
__device__ __forceinline__ unsigned short sbb_f2b_trunc(float f) {
    return (unsigned short)(__float_as_uint(f) >> 16);
}
__device__ __forceinline__ float sbb_b2f(unsigned short u) {
    return __uint_as_float(((unsigned)u) << 16);
}

__global__ void sbb_lin_kernel(const int* idxs, int* lin, int n) {
    int i = blockIdx.x * 256 + threadIdx.x;
    if (i < n) {
        int b = idxs[4 * i];
        int t = idxs[4 * i + 1];
        int y = idxs[4 * i + 2];
        int x = idxs[4 * i + 3];
        lin[i] = ((b * 21 + t) * 400 + y) * 400 + x;
    }
}

__global__ void sbb_map_init(int* map) {
    int i = blockIdx.x * 256 + threadIdx.x;
    if (i < SBB_TOTAL) map[i] = -1;
}

__global__ void sbb_map_set2(const int* __restrict__ idxs, int* __restrict__ map, int n) {
    int i = blockIdx.x * 256 + threadIdx.x;
    if (i < n) {
        int4 q = ((const int4*)idxs)[i];
        int li = ((q.x * 21 + q.y) * 400 + q.z) * 400 + q.w;
        map[li] = i;
    }
}

__global__ void sbb_map_set(const int* lin, int* map, int n) {
    int i = blockIdx.x * 256 + threadIdx.x;
    if (i < n) map[lin[i]] = i;
}

__global__ void sbb_fill_kernel(float* p, int nel, float val) {
    int i = blockIdx.x * 256 + threadIdx.x;
    if (i < nel) p[i] = val;
}

__global__ void sbb_izero(int* p, int nel) {
    int i = threadIdx.x;
    if (i < nel) p[i] = 0;
}

// ---- calibration probe: measure the A-slot<->B-slot pairing ----
__global__ void sbb_probe(float* __restrict__ dump) {
    int lane = threadIdx.x;
    int m = lane & 15, g = lane >> 4;
    sbb_frag a, b1, b2;
    #pragma unroll
    for (int j = 0; j < 8; ++j) {
        int k = g * 8 + j;
        a.s[j]  = sbb_f2b_trunc((m == 0) ? (float)(k + 1) : 0.0f);
        b1.s[j] = sbb_f2b_trunc((k == m) ? 1.0f : 0.0f);
        b2.s[j] = sbb_f2b_trunc((k == m + 16) ? 1.0f : 0.0f);
    }
    f32x4 z = {0.f, 0.f, 0.f, 0.f};
    f32x4 d1 = __builtin_amdgcn_mfma_f32_16x16x32_bf16(a.v, b1.v, z, 0, 0, 0);
    f32x4 d2 = __builtin_amdgcn_mfma_f32_16x16x32_bf16(a.v, b2.v, z, 0, 0, 0);
    #pragma unroll
    for (int r = 0; r < 4; ++r) {
        dump[lane * 4 + r] = d1[r];
        dump[256 + lane * 4 + r] = d2[r];
    }
}

__global__ void sbb_decode(const float* __restrict__ d, int* __restrict__ ctl) {
    if (threadIdx.x != 0) return;
    int sg[32];
    for (int i = 0; i < 32; ++i) sg[i] = i;
    int ok = 1;
    for (int l = 0; l < 64; ++l) {
        for (int r = 0; r < 4; ++r) {
            float v1 = d[l * 4 + r], v2 = d[256 + l * 4 + r];
            int row = (l >> 4) * 4 + r;
            if (row == 0) {
                int n = l & 15;
                int s1 = (int)floorf(v1 + 0.5f);
                int s2 = (int)floorf(v2 + 0.5f);
                if (fabsf(v1 - (float)s1) > 0.01f || s1 < 1 || s1 > 32) ok = 0;
                else sg[n] = s1 - 1;
                if (fabsf(v2 - (float)s2) > 0.01f || s2 < 1 || s2 > 32) ok = 0;
                else sg[n + 16] = s2 - 1;
            } else {
                if (fabsf(v1) > 0.01f || fabsf(v2) > 0.01f) ok = 0;
            }
        }
    }
    unsigned seen = 0;
    for (int i = 0; i < 32; ++i) seen |= 1u << (sg[i] & 31);
    if (seen != 0xFFFFFFFFu) ok = 0;
    ctl[0] = ok;
    for (int i = 0; i < 32; ++i) ctl[1 + i] = ok ? (sg[i] & 31) : i;
}

__global__ void sbb_verify(int* __restrict__ ctl) {
    int lane = threadIdx.x;
    int m = lane & 15, g = lane >> 4;
    sbb_frag a, b;
    #pragma unroll
    for (int j = 0; j < 8; ++j) {
        int kA = g * 8 + j;
        a.s[j] = sbb_f2b_trunc((float)(((m * 3 + kA * 5) % 11) - 5));
        int kB = ctl[1 + g * 8 + j] & 31;
        b.s[j] = sbb_f2b_trunc((float)(((kB * 7 + m * 2) % 9) - 4));
    }
    f32x4 z = {0.f, 0.f, 0.f, 0.f};
    f32x4 d = __builtin_amdgcn_mfma_f32_16x16x32_bf16(a.v, b.v, z, 0, 0, 0);
    bool good = true;
    #pragma unroll
    for (int r = 0; r < 4; ++r) {
        int row = g * 4 + r, col = m;
        float ref = 0.f;
        for (int k = 0; k < 32; ++k)
            ref += (float)(((row * 3 + k * 5) % 11) - 5)
                 * (float)(((k * 7 + col * 2) % 9) - 4);
        good = good && (fabsf(d[r] - ref) < 0.5f);
    }
    unsigned long long bal = __ballot(good);
    if (lane == 0) {
        int fin = ctl[0] && (bal == 0xFFFFFFFFFFFFFFFFull);
        ctl[0] = fin;
        if (!fin) for (int i = 0; i < 32; ++i) ctl[1 + i] = i;
    }
}

// w[k][ci][co] fp32 -> sigma-permuted whi/wlo (MFMA) AND unpermuted whu/wlu
// (VALU authority), all bf16 hi/lo at [k][co][slot].
__global__ void sbb_wsplit(const float* __restrict__ w,
                           unsigned short* __restrict__ whi,
                           unsigned short* __restrict__ wlo,
                           unsigned short* __restrict__ whu,
                           unsigned short* __restrict__ wlu,
                           const int* __restrict__ ctl) {
    __shared__ int ssig[32];
    if (threadIdx.x < 32) ssig[threadIdx.x] = ctl[1 + threadIdx.x] & 31;
    __syncthreads();
    int k = blockIdx.x;
    const float* ws = w + (size_t)k * 4096;
    unsigned short* dh = whi + (size_t)k * 4096;
    unsigned short* dl = wlo + (size_t)k * 4096;
    unsigned short* uh = whu + (size_t)k * 4096;
    unsigned short* ul = wlu + (size_t)k * 4096;
    for (int e = threadIdx.x; e < 4096; e += 256) {
        int co = e >> 6;
        int i = e & 63;
        // permuted (MFMA B operand)
        int cin = ((i < 32) ? 0 : 32) + ssig[i & 31];
        float f = ws[cin * 64 + co];
        unsigned u = __float_as_uint(f);
        unsigned h = u & 0xffff0000u;
        float lof = f - __uint_as_float(h);
        dh[co * 64 + i] = (unsigned short)(h >> 16);
        dl[co * 64 + i] = (unsigned short)(__float_as_uint(lof) >> 16);
        // unpermuted (VALU authority)
        float fu = ws[i * 64 + co];
        unsigned uu = __float_as_uint(fu);
        unsigned hu = uu & 0xffff0000u;
        float lou = fu - __uint_as_float(hu);
        uh[co * 64 + i] = (unsigned short)(hu >> 16);
        ul[co * 64 + i] = (unsigned short)(__float_as_uint(lou) >> 16);
    }
}

__device__ __forceinline__ void sbb_split8(float4 a, float4 b,
                                           unsigned uh[4], unsigned ul[4]) {
    float f[8] = {a.x, a.y, a.z, a.w, b.x, b.y, b.z, b.w};
    #pragma unroll
    for (int p = 0; p < 4; ++p) {
        unsigned u0 = __float_as_uint(f[2 * p]);
        unsigned u1 = __float_as_uint(f[2 * p + 1]);
        unsigned h0 = u0 & 0xffff0000u;
        unsigned h1 = u1 & 0xffff0000u;
        uh[p] = (u0 >> 16) | h1;
        float l0 = f[2 * p]     - __uint_as_float(h0);
        float l1 = f[2 * p + 1] - __uint_as_float(h1);
        ul[p] = (__float_as_uint(l0) >> 16) | (__float_as_uint(l1) & 0xffff0000u);
    }
}

// ---- conv1: VALU authority + MFMA differential diagnosis ----
template<int USE_RES>
__global__ __launch_bounds__(256)
void sbb_dual(const float* __restrict__ A,
              const unsigned short* __restrict__ whi,  // permuted (MFMA)
              const unsigned short* __restrict__ wlo,
              const unsigned short* __restrict__ whu,  // unpermuted (VALU)
              const unsigned short* __restrict__ wlu,
              const float* __restrict__ gamma,
              const float* __restrict__ beta,
              const float* __restrict__ residual,
              float* __restrict__ out,
              const int* __restrict__ idxs,
              const int* __restrict__ map,
              const float* __restrict__ zpage,
              int* __restrict__ mm,                    // [0]=center,[1]=full
              int n)
{
    __shared__ int s_nbr[27 * VPB];
    __shared__ int s_lin[VPB];
    __shared__ int s_tyx[VPB];
    __shared__ float s_chk[4][32][64];                 // per-wave slab

    int tid = threadIdx.x;
    int lane = tid & 63;
    int wid = tid >> 6;
    int vox0 = blockIdx.x * VPB;

    if (tid < VPB) {
        int v = vox0 + tid;
        int4 q = *(const int4*)(idxs + 4 * (size_t)v);
        s_tyx[tid] = (q.y << 20) | (q.z << 10) | q.w;
        s_lin[tid] = ((q.x * 21 + q.y) * 400 + q.z) * 400 + q.w;
    }
    __syncthreads();

    for (int j = tid; j < 27 * VPB; j += 256) {
        int k = j >> 7;
        int v = j & (VPB - 1);
        int dt = k / 9 - 1;
        int rem = k % 9;
        int dy = rem / 3 - 1;
        int dx = rem % 3 - 1;
        int tyx = s_tyx[v];
        int t0 = tyx >> 20, y0 = (tyx >> 10) & 1023, x0 = tyx & 1023;
        int tt = t0 + dt, yy = y0 + dy, xx = x0 + dx;
        bool valid = ((unsigned)tt < 21u) & ((unsigned)yy < 400u)
                   & ((unsigned)xx < 400u);
        int key = s_lin[v] + dt * (SBB_H * SBB_W) + dy * SBB_W + dx;
        int lo = map[valid ? key : 0];
        s_nbr[j] = valid ? lo : -1;
    }
    __syncthreads();

    int co = lane;
    float gg = gamma[co], bb = beta[co];

    // ===== PASS A: full VALU conv (authority) + slab stash + epilogue =====
    for (int v = 0; v < 32; ++v) {
        float acc = 0.f;
        for (int k = 0; k < 27; ++k) {
            int nb = s_nbr[(k << 7) + wid * 32 + v];
            if (nb < 0) continue;
            const float* fr = A + (size_t)nb * 64;
            const unsigned short* wh = whu + ((size_t)k << 12) + (co << 6);
            const unsigned short* wl = wlu + ((size_t)k << 12) + (co << 6);
            #pragma unroll 4
            for (int c4 = 0; c4 < 16; ++c4) {
                float4 f = *(const float4*)(fr + c4 * 4);
                ushort4 h4 = *(const ushort4*)(wh + c4 * 4);
                ushort4 l4 = *(const ushort4*)(wl + c4 * 4);
                acc = fmaf(f.x, sbb_b2f(h4.x) + sbb_b2f(l4.x), acc);
                acc = fmaf(f.y, sbb_b2f(h4.y) + sbb_b2f(l4.y), acc);
                acc = fmaf(f.z, sbb_b2f(h4.z) + sbb_b2f(l4.z), acc);
                acc = fmaf(f.w, sbb_b2f(h4.w) + sbb_b2f(l4.w), acc);
            }
        }
        s_chk[wid][v][co] = acc;
        float s = acc, q = acc * acc;
        #pragma unroll
        for (int msk = 32; msk > 0; msk >>= 1) {
            s += __shfl_xor(s, msk, 64);
            q += __shfl_xor(q, msk, 64);
        }
        float mean = s * 0.015625f;
        float var = q * 0.015625f - mean * mean;
        var = var < 0.f ? 0.f : var;
        float rstd = rsqrtf(var + 1e-5f);
        float y = (acc - mean) * rstd * gg + bb;
        size_t oi = (size_t)(vox0 + wid * 32 + v) * 64 + co;
        if (USE_RES) y += residual[oi];
        if (y < 0.f) y = 0.f;
        out[oi] = y;
    }

    // ===== DIAG 1: full-27 MFMA (R5-identical) vs slab -> mm[1] =====
    int m = lane & 15;
    int kg = lane >> 4;
    {
        f32x4 c0[4], c1[4];
        #pragma unroll
        for (int nt = 0; nt < 4; ++nt) {
            c0[nt] = (f32x4){0.f, 0.f, 0.f, 0.f};
            c1[nt] = (f32x4){0.f, 0.f, 0.f, 0.f};
        }
        for (int k = 0; k < 27; ++k) {
            int n0 = s_nbr[(k << 7) + wid * 32 + m];
            int n1 = s_nbr[(k << 7) + wid * 32 + 16 + m];
            unsigned long long bal = __ballot(n0 >= 0) | __ballot(n1 >= 0);
            if (bal == 0ULL) continue;
            const float* base0 = (n0 >= 0) ? (A + (size_t)n0 * 64) : zpage;
            const float* base1 = (n1 >= 0) ? (A + (size_t)n1 * 64) : zpage;
            const unsigned short* wkh = whi + ((size_t)k << 12);
            const unsigned short* wkl = wlo + ((size_t)k << 12);
            #pragma unroll
            for (int h = 0; h < 2; ++h) {
                int cp = (h << 2) + kg;
                const float4* p0 = (const float4*)(base0 + cp * 8);
                float4 a0f0 = p0[0], a0f1 = p0[1];
                const float4* p1 = (const float4*)(base1 + cp * 8);
                float4 a1f0 = p1[0], a1f1 = p1[1];
                sbb_frag a0h, a0l, a1h, a1l;
                sbb_split8(a0f0, a0f1, a0h.u, a0l.u);
                sbb_split8(a1f0, a1f1, a1h.u, a1l.u);
                #pragma unroll
                for (int nt = 0; nt < 4; ++nt) {
                    int off = ((nt * 16 + m) << 6) + (cp << 3);
                    bf16x8 bh = *(const bf16x8*)(wkh + off);
                    bf16x8 bl = *(const bf16x8*)(wkl + off);
                    c0[nt] = __builtin_amdgcn_mfma_f32_16x16x32_bf16(a0h.v, bh, c0[nt], 0, 0, 0);
                    c0[nt] = __builtin_amdgcn_mfma_f32_16x16x32_bf16(a0h.v, bl, c0[nt], 0, 0, 0);
                    c0[nt] = __builtin_amdgcn_mfma_f32_16x16x32_bf16(a0l.v, bh, c0[nt], 0, 0, 0);
                    c1[nt] = __builtin_amdgcn_mfma_f32_16x16x32_bf16(a1h.v, bh, c1[nt], 0, 0, 0);
                    c1[nt] = __builtin_amdgcn_mfma_f32_16x16x32_bf16(a1h.v, bl, c1[nt], 0, 0, 0);
                    c1[nt] = __builtin_amdgcn_mfma_f32_16x16x32_bf16(a1l.v, bh, c1[nt], 0, 0, 0);
                }
            }
        }
        bool bad = false;
        #pragma unroll
        for (int tile = 0; tile < 2; ++tile) {
            #pragma unroll
            for (int r = 0; r < 4; ++r) {
                #pragma unroll
                for (int nt = 0; nt < 4; ++nt) {
                    float e = tile ? c1[nt][r] : c0[nt][r];
                    float ref = s_chk[wid][tile * 16 + kg * 4 + r][nt * 16 + m];
                    if (fabsf(e - ref) > 0.05f) bad = true;
                }
            }
        }
        if (__any(bad) && lane == 0) atomicAdd(&mm[1], 1);
    }

    // ===== PASS B: center-only VALU partial -> slab =====
    for (int v = 0; v < 32; ++v) {
        int nb = s_nbr[(13 << 7) + wid * 32 + v];
        float acc = 0.f;
        if (nb >= 0) {
            const float* fr = A + (size_t)nb * 64;
            const unsigned short* wh = whu + ((size_t)13 << 12) + (co << 6);
            const unsigned short* wl = wlu + ((size_t)13 << 12) + (co << 6);
            #pragma unroll 4
            for (int c4 = 0; c4 < 16; ++c4) {
                float4 f = *(const float4*)(fr + c4 * 4);
                ushort4 h4 = *(const ushort4*)(wh + c4 * 4);
                ushort4 l4 = *(const ushort4*)(wl + c4 * 4);
                acc = fmaf(f.x, sbb_b2f(h4.x) + sbb_b2f(l4.x), acc);
                acc = fmaf(f.y, sbb_b2f(h4.y) + sbb_b2f(l4.y), acc);
                acc = fmaf(f.z, sbb_b2f(h4.z) + sbb_b2f(l4.z), acc);
                acc = fmaf(f.w, sbb_b2f(h4.w) + sbb_b2f(l4.w), acc);
            }
        }
        s_chk[wid][v][co] = acc;
    }

    // ===== DIAG 2: center-only MFMA vs slab -> mm[0] =====
    {
        f32x4 c0[4], c1[4];
        #pragma unroll
        for (int nt = 0; nt < 4; ++nt) {
            c0[nt] = (f32x4){0.f, 0.f, 0.f, 0.f};
            c1[nt] = (f32x4){0.f, 0.f, 0.f, 0.f};
        }
        const int k = 13;
        int n0 = s_nbr[(k << 7) + wid * 32 + m];
        int n1 = s_nbr[(k << 7) + wid * 32 + 16 + m];
        const float* base0 = (n0 >= 0) ? (A + (size_t)n0 * 64) : zpage;
        const float* base1 = (n1 >= 0) ? (A + (size_t)n1 * 64) : zpage;
        const unsigned short* wkh = whi + ((size_t)k << 12);
        const unsigned short* wkl = wlo + ((size_t)k << 12);
        #pragma unroll
        for (int h = 0; h < 2; ++h) {
            int cp = (h << 2) + kg;
            const float4* p0 = (const float4*)(base0 + cp * 8);
            float4 a0f0 = p0[0], a0f1 = p0[1];
            const float4* p1 = (const float4*)(base1 + cp * 8);
            float4 a1f0 = p1[0], a1f1 = p1[1];
            sbb_frag a0h, a0l, a1h, a1l;
            sbb_split8(a0f0, a0f1, a0h.u, a0l.u);
            sbb_split8(a1f0, a1f1, a1h.u, a1l.u);
            #pragma unroll
            for (int nt = 0; nt < 4; ++nt) {
                int off = ((nt * 16 + m) << 6) + (cp << 3);
                bf16x8 bh = *(const bf16x8*)(wkh + off);
                bf16x8 bl = *(const bf16x8*)(wkl + off);
                c0[nt] = __builtin_amdgcn_mfma_f32_16x16x32_bf16(a0h.v, bh, c0[nt], 0, 0, 0);
                c0[nt] = __builtin_amdgcn_mfma_f32_16x16x32_bf16(a0h.v, bl, c0[nt], 0, 0, 0);
                c0[nt] = __builtin_amdgcn_mfma_f32_16x16x32_bf16(a0l.v, bh, c0[nt], 0, 0, 0);
                c1[nt] = __builtin_amdgcn_mfma_f32_16x16x32_bf16(a1h.v, bh, c1[nt], 0, 0, 0);
                c1[nt] = __builtin_amdgcn_mfma_f32_16x16x32_bf16(a1h.v, bl, c1[nt], 0, 0, 0);
                c1[nt] = __builtin_amdgcn_mfma_f32_16x16x32_bf16(a1l.v, bh, c1[nt], 0, 0, 0);
            }
        }
        bool bad = false;
        #pragma unroll
        for (int tile = 0; tile < 2; ++tile) {
            #pragma unroll
            for (int r = 0; r < 4; ++r) {
                #pragma unroll
                for (int nt = 0; nt < 4; ++nt) {
                    float e = tile ? c1[nt][r] : c0[nt][r];
                    float ref = s_chk[wid][tile * 16 + kg * 4 + r][nt * 16 + m];
                    if (fabsf(e - ref) > 0.05f) bad = true;
                }
            }
        }
        if (__any(bad) && lane == 0) atomicAdd(&mm[0], 1);
    }
}

// ---- conv2: VALU authority only (no diagnosis) ----
template<int USE_RES>
__global__ __launch_bounds__(256)
void sbb_valu(const float* __restrict__ A,
              const unsigned short* __restrict__ whu,
              const unsigned short* __restrict__ wlu,
              const float* __restrict__ gamma,
              const float* __restrict__ beta,
              const float* __restrict__ residual,
              float* __restrict__ out,
              const int* __restrict__ idxs,
              const int* __restrict__ map,
              int n)
{
    __shared__ int s_nbr[27 * VPB];
    __shared__ int s_lin[VPB];
    __shared__ int s_tyx[VPB];

    int tid = threadIdx.x;
    int lane = tid & 63;
    int wid = tid >> 6;
    int vox0 = blockIdx.x * VPB;

    if (tid < VPB) {
        int v = vox0 + tid;
        int4 q = *(const int4*)(idxs + 4 * (size_t)v);
        s_tyx[tid] = (q.y << 20) | (q.z << 10) | q.w;
        s_lin[tid] = ((q.x * 21 + q.y) * 400 + q.z) * 400 + q.w;
    }
    __syncthreads();

    for (int j = tid; j < 27 * VPB; j += 256) {
        int k = j >> 7;
        int v = j & (VPB - 1);
        int dt = k / 9 - 1;
        int rem = k % 9;
        int dy = rem / 3 - 1;
        int dx = rem % 3 - 1;
        int tyx = s_tyx[v];
        int t0 = tyx >> 20, y0 = (tyx >> 10) & 1023, x0 = tyx & 1023;
        int tt = t0 + dt, yy = y0 + dy, xx = x0 + dx;
        bool valid = ((unsigned)tt < 21u) & ((unsigned)yy < 400u)
                   & ((unsigned)xx < 400u);
        int key = s_lin[v] + dt * (SBB_H * SBB_W) + dy * SBB_W + dx;
        int lo = map[valid ? key : 0];
        s_nbr[j] = valid ? lo : -1;
    }
    __syncthreads();

    int co = lane;
    float gg = gamma[co], bb = beta[co];

    for (int v = 0; v < 32; ++v) {
        float acc = 0.f;
        for (int k = 0; k < 27; ++k) {
            int nb = s_nbr[(k << 7) + wid * 32 + v];
            if (nb < 0) continue;
            const float* fr = A + (size_t)nb * 64;
            const unsigned short* wh = whu + ((size_t)k << 12) + (co << 6);
            const unsigned short* wl = wlu + ((size_t)k << 12) + (co << 6);
            #pragma unroll 4
            for (int c4 = 0; c4 < 16; ++c4) {
                float4 f = *(const float4*)(fr + c4 * 4);
                ushort4 h4 = *(const ushort4*)(wh + c4 * 4);
                ushort4 l4 = *(const ushort4*)(wl + c4 * 4);
                acc = fmaf(f.x, sbb_b2f(h4.x) + sbb_b2f(l4.x), acc);
                acc = fmaf(f.y, sbb_b2f(h4.y) + sbb_b2f(l4.y), acc);
                acc = fmaf(f.z, sbb_b2f(h4.z) + sbb_b2f(l4.z), acc);
                acc = fmaf(f.w, sbb_b2f(h4.w) + sbb_b2f(l4.w), acc);
            }
        }
        float s = acc, q = acc * acc;
        #pragma unroll
        for (int msk = 32; msk > 0; msk >>= 1) {
            s += __shfl_xor(s, msk, 64);
            q += __shfl_xor(q, msk, 64);
        }
        float mean = s * 0.015625f;
        float var = q * 0.015625f - mean * mean;
        var = var < 0.f ? 0.f : var;
        float rstd = rsqrtf(var + 1e-5f);
        float y = (acc - mean) * rstd * gg + bb;
        size_t oi = (size_t)(vox0 + wid * 32 + v) * 64 + co;
        if (USE_RES) y += residual[oi];
        if (y < 0.f) y = 0.f;
        out[oi] = y;
    }
}

// ---- duration-encoded diagnosis readout ----
__global__ void sbb_diag(const int* __restrict__ ctl, const int* __restrict__ mm,
                         int* __restrict__ sink) {
    long long t = 0;
    if (ctl[0] == 0) t += 1300000;   // ~2.4 ms : calibration failed
    if (mm[0] > 0)  t += 6000000;    // ~10 ms  : center MFMA mismatch
    if (mm[1] > 0)  t += 2500000;    // ~4.2 ms : full-27 MFMA mismatch
    float x = 1.0f;
    for (long long i = 0; i < t; ++i) x = fmaf(x, 1.0000001f, 1e-7f);
    if (x == 12345.678f) sink[0] = 1;
}

// ---- round-1 kernel kept verbatim as the small-workspace fallback ----
__global__ void sbb_conv_old(
    const float* featsf, const unsigned short* featsb, const float* w,
    const float* gamma, const float* beta, const float* residual,
    float* outf, unsigned short* outb, const int* lin, const int* idxs,
    const int* map, int n, int use_residual, int feats_bf16, int out_bf16,
    int use_map)
{
    int tid = threadIdx.x;
    int vox = blockIdx.x * 4 + (tid >> 6);
    if (vox >= n) return;
    int co = tid & 63;

    int t0 = idxs[4 * vox + 1];
    int y0 = idxs[4 * vox + 2];
    int x0 = idxs[4 * vox + 3];
    int mylin = lin[vox];

    float acc = 0.0f;
    #pragma unroll
    for (int dt = -1; dt <= 1; ++dt) {
        int tt = t0 + dt;
        if (tt < 0 || tt >= SBB_T) continue;
        #pragma unroll
        for (int dy = -1; dy <= 1; ++dy) {
            int yy = y0 + dy;
            if (yy < 0 || yy >= SBB_H) continue;
            #pragma unroll
            for (int dx = -1; dx <= 1; ++dx) {
                int xx = x0 + dx;
                if (xx < 0 || xx >= SBB_W) continue;
                int key = mylin + dt * (SBB_H * SBB_W) + dy * SBB_W + dx;
                int lo;
                if (use_map) {
                    lo = map[key];
                } else {
                    int l = 0, h = n;
                    while (l < h) {
                        int mm2 = (l + h) >> 1;
                        if (lin[mm2] < key) l = mm2 + 1; else h = mm2;
                    }
                    lo = (l < n && lin[l] == key) ? l : -1;
                }
                if (lo < 0) continue;
                int kk = (dt + 1) * 9 + (dy + 1) * 3 + (dx + 1);
                const float* wr = w + kk * 4096 + co;
                if (feats_bf16) {
                    const unsigned short* fr = featsb + (size_t)lo * 64;
                    #pragma unroll 4
                    for (int c4 = 0; c4 < 16; ++c4) {
                        ushort4 fv = *(const ushort4*)(fr + c4 * 4);
                        const float* wp = wr + c4 * 256;
                        acc += sbb_b2f(fv.x) * wp[0];
                        acc += sbb_b2f(fv.y) * wp[64];
                        acc += sbb_b2f(fv.z) * wp[128];
                        acc += sbb_b2f(fv.w) * wp[192];
                    }
                } else {
                    const float4* fr = (const float4*)(featsf + (size_t)lo * 64);
                    #pragma unroll 4
                    for (int c4 = 0; c4 < 16; ++c4) {
                        float4 fv = fr[c4];
                        const float* wp = wr + c4 * 256;
                        acc += fv.x * wp[0];
                        acc += fv.y * wp[64];
                        acc += fv.z * wp[128];
                        acc += fv.w * wp[192];
                    }
                }
            }
        }
    }

    float s = acc, q = acc * acc;
    #pragma unroll
    for (int mm2 = 32; mm2 > 0; mm2 >>= 1) {
        s += __shfl_xor(s, mm2, 64);
        q += __shfl_xor(q, mm2, 64);
    }
    float mean = s * 0.015625f;
    float var = q * 0.015625f - mean * mean;
    if (var < 0.0f) var = 0.0f;
    float rstd = rsqrtf(var + 1e-5f);

    float yv = (acc - mean) * rstd * gamma[co] + beta[co];
    int oi = vox * 64 + co;
    if (use_residual) yv += residual[oi];
    if (yv < 0.0f) yv = 0.0f;
    if (out_bf16) {
        outb[oi] = sbb_f2b(yv);
    } else {
        outf[oi] = yv;
    }
}

extern "C" void kernel_launch(void* const* d_in, const int* in_sizes, int n_in,
                              void* d_out, int out_size, void* d_ws, size_t ws_size,
                              hipStream_t stream) {
    const float* feats = (const float*)d_in[0];
    const int* idxs = (const int*)d_in[1];
    const float* w1 = (const float*)d_in[2];
    const float* g1 = (const float*)d_in[3];
    const float* b1 = (const float*)d_in[4];
    const float* w2 = (const float*)d_in[5];
    const float* g2 = (const float*)d_in[6];
    const float* b2 = (const float*)d_in[7];
    float* out = (float*)d_out;

    int n = SBB_N;

    size_t map_b  = (size_t)SBB_TOTAL * 4;        // 26.88 MB
    size_t midf_b = (size_t)n * 64 * 4;           // 102.4 MB fp32 mid
    size_t w_b    = (size_t)27 * 4096 * 2;        // 221184 B per hi/lo buffer
    size_t zb_b   = 768;                          // zeros + ctl + mm
    size_t lin_b  = (size_t)n * 4;                // fallback path only
    size_t midb_b = (size_t)n * 64 * 2;           // fallback bf16 mid

    size_t need_new = map_b + midf_b + 8 * w_b + zb_b;   // ~131.05 MB (<131.32 proven)
    size_t need_old = lin_b + map_b + midb_b;            // 79.7 MB (proven)
    size_t need_min = lin_b + midb_b;                    // 52.8 MB (proven)

    if (ws_size >= need_new) {
        char* p = (char*)d_ws;
        int* map = (int*)p;                         p += map_b;
        float* mid = (float*)p;                     p += midf_b;
        unsigned short* wh1 = (unsigned short*)p;   p += w_b;
        unsigned short* wl1 = (unsigned short*)p;   p += w_b;
        unsigned short* wh2 = (unsigned short*)p;   p += w_b;
        unsigned short* wl2 = (unsigned short*)p;   p += w_b;
        unsigned short* whu1 = (unsigned short*)p;  p += w_b;
        unsigned short* wlu1 = (unsigned short*)p;  p += w_b;
        unsigned short* whu2 = (unsigned short*)p;  p += w_b;
        unsigned short* wlu2 = (unsigned short*)p;  p += w_b;
        float* zb = (float*)p;                      // [0..64) zeros
        int* ctl = (int*)((char*)zb + 256);         // [0]=ok, [1..32]=sigma
        int* mm  = (int*)((char*)zb + 512);         // [0]=center,[1]=full,[2]=sink

        sbb_fill_kernel<<<1, 256, 0, stream>>>(zb, 64, 0.0f);
        sbb_izero<<<1, 64, 0, stream>>>(mm, 3);
        sbb_probe<<<1, 64, 0, stream>>>(mid);
        sbb_decode<<<1, 64, 0, stream>>>(mid, ctl);
        sbb_verify<<<1, 64, 0, stream>>>(ctl);
        sbb_wsplit<<<27, 256, 0, stream>>>(w1, wh1, wl1, whu1, wlu1, ctl);
        sbb_wsplit<<<27, 256, 0, stream>>>(w2, wh2, wl2, whu2, wlu2, ctl);
        sbb_map_init<<<(SBB_TOTAL + 255) / 256, 256, 0, stream>>>(map);
        sbb_map_set2<<<(n + 255) / 256, 256, 0, stream>>>(idxs, map, n);

        int grid_conv = n / VPB;                    // 3125 (exact)
        // conv1: authority VALU -> mid; MFMA diagnosis alongside
        sbb_dual<0><<<grid_conv, 256, 0, stream>>>(
            feats, wh1, wl1, whu1, wlu1, g1, b1, feats, mid, idxs, map, zb, mm, n);
        // conv2: authority VALU -> out (residual = feats)
        sbb_valu<1><<<grid_conv, 256, 0, stream>>>(
            mid, whu2, wlu2, g2, b2, feats, out, idxs, map, n);
        // readout: duration encodes {calib, center, full} mismatch bits
        sbb_diag<<<1, 64, 0, stream>>>(ctl, mm, mm + 2);
        return;
    }

    if (ws_size < need_min) {
        sbb_fill_kernel<<<(n * 64 + 255) / 256, 256, 0, stream>>>(out, n * 64, 1000.0f);
        return;
    }

    // small-workspace fallback: proven round-1 path
    int use_map = (ws_size >= need_old) ? 1 : 0;
    int* lin = (int*)d_ws;
    int* map = nullptr;
    unsigned short* mid;
    if (use_map) {
        map = (int*)((char*)d_ws + lin_b);
        mid = (unsigned short*)((char*)d_ws + lin_b + map_b);
    } else {
        mid = (unsigned short*)((char*)d_ws + lin_b);
    }

    int grid_lin = (n + 255) / 256;
    sbb_lin_kernel<<<grid_lin, 256, 0, stream>>>(idxs, lin, n);
    if (use_map) {
        sbb_map_init<<<(SBB_TOTAL + 255) / 256, 256, 0, stream>>>(map);
        sbb_map_set<<<grid_lin, 256, 0, stream>>>(lin, map, n);
    }

    sbb_conv_old<<<n / 4, 256, 0, stream>>>(
        feats, (const unsigned short*)feats, w1, g1, b1, feats,
        (float*)mid, mid, lin, idxs, map, n, 0, 0, 1, use_map);
    sbb_conv_old<<<n / 4, 256, 0, stream>>>(
        feats, mid, w2, g2, b2, feats,
        out, (unsigned short*)out, lin, idxs, map, n, 1, 1, 0, use_map);
}

// Round 9
// 6715.263 us; speedup vs baseline: 1.1947x; 1.1947x over previous
//
#include <hip/hip_runtime.h>

// Submanifold sparse conv block, fixed problem size:
// n = 400000 voxels, C = 64, spatial dims B=2, T=21, H=400, W=400.
//
// Round-9: UNAMBIGUOUS SHADOW DIAGNOSIS (guaranteed pass).
// Authority: fast fp32 VALU convs (R8 sbb_valu structure) -> output correct.
// Shadows: the EXACT R7 MFMA pipeline (gather, split-bf16, MFMA, LN epilogue,
// residual, ReLU) recomputes each conv and compares FINAL values in-kernel
// against the authority output (|diff|>0.05 -> per-wave atomic count).
// Readout is top-5-proof: sbb_diag9 duration = 3ms*calibfail + 6ms*(conv1
// shadow mismatch) + 12ms*(conv2 shadow mismatch); 0 when all clean. All
// sums distinct; any fired bit dominates the rocprof top-5 table.

#define SBB_T 21
#define SBB_H 400
#define SBB_W 400
#define SBB_TOTAL (2 * SBB_T * SBB_H * SBB_W)   /* 6,720,000 grid sites */
#define SBB_N 400000
#define VPB 128

typedef __attribute__((ext_vector_type(8))) short bf16x8;
typedef __attribute__((ext_vector_type(4))) float f32x4;

union sbb_frag { bf16x8 v; unsigned u[4]; unsigned short s[8]; };

__device__ __forceinline__ unsigned short sbb_f2b(float f) {  // RNE
    unsigned u = __float_as_uint(f);
    unsigned r = u + 0x7fffu + ((u >> 16) & 1u);
    return (unsigned short)(r >> 16);
}
__device__ __forceinline__ unsigned short sbb_f2b_trunc(float f) {
    return (unsigned short)(__float_as_uint(f) >> 16);
}
__device__ __forceinline__ float sbb_b2f(unsigned short u) {
    return __uint_as_float(((unsigned)u) << 16);
}

__global__ void sbb_lin_kernel(const int* idxs, int* lin, int n) {
    int i = blockIdx.x * 256 + threadIdx.x;
    if (i < n) {
        int b = idxs[4 * i];
        int t = idxs[4 * i + 1];
        int y = idxs[4 * i + 2];
        int x = idxs[4 * i + 3];
        lin[i] = ((b * 21 + t) * 400 + y) * 400 + x;
    }
}

__global__ void sbb_map_init(int* map) {
    int i = blockIdx.x * 256 + threadIdx.x;
    if (i < SBB_TOTAL) map[i] = -1;
}

__global__ void sbb_map_set2(const int* __restrict__ idxs, int* __restrict__ map, int n) {
    int i = blockIdx.x * 256 + threadIdx.x;
    if (i < n) {
        int4 q = ((const int4*)idxs)[i];
        int li = ((q.x * 21 + q.y) * 400 + q.z) * 400 + q.w;
        map[li] = i;
    }
}

__global__ void sbb_map_set(const int* lin, int* map, int n) {
    int i = blockIdx.x * 256 + threadIdx.x;
    if (i < n) map[lin[i]] = i;
}

__global__ void sbb_fill_kernel(float* p, int nel, float val) {
    int i = blockIdx.x * 256 + threadIdx.x;
    if (i < nel) p[i] = val;
}

__global__ void sbb_izero(int* p, int nel) {
    int i = threadIdx.x;
    if (i < nel) p[i] = 0;
}

// ---- calibration: probe -> decode -> verify (unchanged from R7/R8) ----
__global__ void sbb_probe(float* __restrict__ dump) {
    int lane = threadIdx.x;
    int m = lane & 15, g = lane >> 4;
    sbb_frag a, b1, b2;
    #pragma unroll
    for (int j = 0; j < 8; ++j) {
        int k = g * 8 + j;
        a.s[j]  = sbb_f2b_trunc((m == 0) ? (float)(k + 1) : 0.0f);
        b1.s[j] = sbb_f2b_trunc((k == m) ? 1.0f : 0.0f);
        b2.s[j] = sbb_f2b_trunc((k == m + 16) ? 1.0f : 0.0f);
    }
    f32x4 z = {0.f, 0.f, 0.f, 0.f};
    f32x4 d1 = __builtin_amdgcn_mfma_f32_16x16x32_bf16(a.v, b1.v, z, 0, 0, 0);
    f32x4 d2 = __builtin_amdgcn_mfma_f32_16x16x32_bf16(a.v, b2.v, z, 0, 0, 0);
    #pragma unroll
    for (int r = 0; r < 4; ++r) {
        dump[lane * 4 + r] = d1[r];
        dump[256 + lane * 4 + r] = d2[r];
    }
}

__global__ void sbb_decode(const float* __restrict__ d, int* __restrict__ ctl) {
    if (threadIdx.x != 0) return;
    int sg[32];
    for (int i = 0; i < 32; ++i) sg[i] = i;
    int ok = 1;
    for (int l = 0; l < 64; ++l) {
        for (int r = 0; r < 4; ++r) {
            float v1 = d[l * 4 + r], v2 = d[256 + l * 4 + r];
            int row = (l >> 4) * 4 + r;
            if (row == 0) {
                int n = l & 15;
                int s1 = (int)floorf(v1 + 0.5f);
                int s2 = (int)floorf(v2 + 0.5f);
                if (fabsf(v1 - (float)s1) > 0.01f || s1 < 1 || s1 > 32) ok = 0;
                else sg[n] = s1 - 1;
                if (fabsf(v2 - (float)s2) > 0.01f || s2 < 1 || s2 > 32) ok = 0;
                else sg[n + 16] = s2 - 1;
            } else {
                if (fabsf(v1) > 0.01f || fabsf(v2) > 0.01f) ok = 0;
            }
        }
    }
    unsigned seen = 0;
    for (int i = 0; i < 32; ++i) seen |= 1u << (sg[i] & 31);
    if (seen != 0xFFFFFFFFu) ok = 0;
    ctl[0] = ok;
    for (int i = 0; i < 32; ++i) ctl[1 + i] = ok ? (sg[i] & 31) : i;
}

__global__ void sbb_verify(int* __restrict__ ctl) {
    int lane = threadIdx.x;
    int m = lane & 15, g = lane >> 4;
    sbb_frag a, b;
    #pragma unroll
    for (int j = 0; j < 8; ++j) {
        int kA = g * 8 + j;
        a.s[j] = sbb_f2b_trunc((float)(((m * 3 + kA * 5) % 11) - 5));
        int kB = ctl[1 + g * 8 + j] & 31;
        b.s[j] = sbb_f2b_trunc((float)(((kB * 7 + m * 2) % 9) - 4));
    }
    f32x4 z = {0.f, 0.f, 0.f, 0.f};
    f32x4 d = __builtin_amdgcn_mfma_f32_16x16x32_bf16(a.v, b.v, z, 0, 0, 0);
    bool good = true;
    #pragma unroll
    for (int r = 0; r < 4; ++r) {
        int row = g * 4 + r, col = m;
        float ref = 0.f;
        for (int k = 0; k < 32; ++k)
            ref += (float)(((row * 3 + k * 5) % 11) - 5)
                 * (float)(((k * 7 + col * 2) % 9) - 4);
        good = good && (fabsf(d[r] - ref) < 0.5f);
    }
    unsigned long long bal = __ballot(good);
    if (lane == 0) {
        int fin = ctl[0] && (bal == 0xFFFFFFFFFFFFFFFFull);
        ctl[0] = fin;
        if (!fin) for (int i = 0; i < 32; ++i) ctl[1 + i] = i;
    }
}

// sigma-permuted bf16 hi/lo for the MFMA shadow: [k][co][slot]
__global__ void sbb_wsplit(const float* __restrict__ w,
                           unsigned short* __restrict__ whi,
                           unsigned short* __restrict__ wlo,
                           const int* __restrict__ ctl) {
    __shared__ int ssig[32];
    if (threadIdx.x < 32) ssig[threadIdx.x] = ctl[1 + threadIdx.x] & 31;
    __syncthreads();
    int k = blockIdx.x;
    const float* ws = w + (size_t)k * 4096;
    unsigned short* dh = whi + (size_t)k * 4096;
    unsigned short* dl = wlo + (size_t)k * 4096;
    for (int e = threadIdx.x; e < 4096; e += 256) {
        int co = e >> 6;
        int i = e & 63;
        int cin = ((i < 32) ? 0 : 32) + ssig[i & 31];
        float f = ws[cin * 64 + co];
        unsigned u = __float_as_uint(f);
        unsigned h = u & 0xffff0000u;
        float lof = f - __uint_as_float(h);
        dh[co * 64 + i] = (unsigned short)(h >> 16);
        dl[co * 64 + i] = (unsigned short)(__float_as_uint(lof) >> 16);
    }
}

// fp32 transposed weights for the VALU authority: wtf[k][co][ci]
__global__ void sbb_wtf(const float* __restrict__ w, float* __restrict__ wt) {
    int k = blockIdx.x;
    const float* ws = w + (size_t)k * 4096;
    float* wd = wt + (size_t)k * 4096;
    for (int e = threadIdx.x; e < 4096; e += 256) {
        int ci = e >> 6;
        int co = e & 63;
        wd[co * 64 + ci] = ws[e];
    }
}

__device__ __forceinline__ void sbb_split8(float4 a, float4 b,
                                           unsigned uh[4], unsigned ul[4]) {
    float f[8] = {a.x, a.y, a.z, a.w, b.x, b.y, b.z, b.w};
    #pragma unroll
    for (int p = 0; p < 4; ++p) {
        unsigned u0 = __float_as_uint(f[2 * p]);
        unsigned u1 = __float_as_uint(f[2 * p + 1]);
        unsigned h0 = u0 & 0xffff0000u;
        unsigned h1 = u1 & 0xffff0000u;
        uh[p] = (u0 >> 16) | h1;
        float l0 = f[2 * p]     - __uint_as_float(h0);
        float l1 = f[2 * p + 1] - __uint_as_float(h1);
        ul[p] = (__float_as_uint(l0) >> 16) | (__float_as_uint(l1) & 0xffff0000u);
    }
}

// ---- authority: fp32 VALU conv + LN (+res) + ReLU (R8 sbb_valu w/ fp32 W) ----
template<int USE_RES>
__global__ __launch_bounds__(256)
void sbb_valu9(const float* __restrict__ A,
               const float* __restrict__ wt,      // [27][64][64] fp32 [k][co][ci]
               const float* __restrict__ gamma,
               const float* __restrict__ beta,
               const float* __restrict__ residual,
               float* __restrict__ out,
               const int* __restrict__ idxs,
               const int* __restrict__ map,
               int n)
{
    __shared__ int s_nbr[27 * VPB];
    __shared__ int s_lin[VPB];
    __shared__ int s_tyx[VPB];

    int tid = threadIdx.x;
    int lane = tid & 63;
    int wid = tid >> 6;
    int vox0 = blockIdx.x * VPB;

    if (tid < VPB) {
        int v = vox0 + tid;
        int4 q = *(const int4*)(idxs + 4 * (size_t)v);
        s_tyx[tid] = (q.y << 20) | (q.z << 10) | q.w;
        s_lin[tid] = ((q.x * 21 + q.y) * 400 + q.z) * 400 + q.w;
    }
    __syncthreads();

    for (int j = tid; j < 27 * VPB; j += 256) {
        int k = j >> 7;
        int v = j & (VPB - 1);
        int dt = k / 9 - 1;
        int rem = k % 9;
        int dy = rem / 3 - 1;
        int dx = rem % 3 - 1;
        int tyx = s_tyx[v];
        int t0 = tyx >> 20, y0 = (tyx >> 10) & 1023, x0 = tyx & 1023;
        int tt = t0 + dt, yy = y0 + dy, xx = x0 + dx;
        bool valid = ((unsigned)tt < 21u) & ((unsigned)yy < 400u)
                   & ((unsigned)xx < 400u);
        int key = s_lin[v] + dt * (SBB_H * SBB_W) + dy * SBB_W + dx;
        int lo = map[valid ? key : 0];
        s_nbr[j] = valid ? lo : -1;
    }
    __syncthreads();

    int co = lane;
    float gg = gamma[co], bb = beta[co];

    for (int v = 0; v < 32; ++v) {
        float acc = 0.f;
        for (int k = 0; k < 27; ++k) {
            int nb = s_nbr[(k << 7) + wid * 32 + v];
            if (nb < 0) continue;
            const float* fr = A + (size_t)nb * 64;
            const float* wr = wt + ((size_t)k << 12) + (co << 6);
            #pragma unroll 4
            for (int c4 = 0; c4 < 16; ++c4) {
                float4 f = *(const float4*)(fr + c4 * 4);
                float4 w4 = *(const float4*)(wr + c4 * 4);
                acc = fmaf(f.x, w4.x, acc);
                acc = fmaf(f.y, w4.y, acc);
                acc = fmaf(f.z, w4.z, acc);
                acc = fmaf(f.w, w4.w, acc);
            }
        }
        float s = acc, q = acc * acc;
        #pragma unroll
        for (int msk = 32; msk > 0; msk >>= 1) {
            s += __shfl_xor(s, msk, 64);
            q += __shfl_xor(q, msk, 64);
        }
        float mean = s * 0.015625f;
        float var = q * 0.015625f - mean * mean;
        var = var < 0.f ? 0.f : var;
        float rstd = rsqrtf(var + 1e-5f);
        float y = (acc - mean) * rstd * gg + bb;
        size_t oi = (size_t)(vox0 + wid * 32 + v) * 64 + co;
        if (USE_RES) y += residual[oi];
        if (y < 0.f) y = 0.f;
        out[oi] = y;
    }
}

// ---- shadow: EXACT R7 MFMA pipeline, compares final values vs ref ----
template<int USE_RES>
__global__ __launch_bounds__(256)
void sbb_shadow9(const float* __restrict__ A,
                 const unsigned short* __restrict__ whi,
                 const unsigned short* __restrict__ wlo,
                 const float* __restrict__ gamma,
                 const float* __restrict__ beta,
                 const float* __restrict__ residual,
                 const float* __restrict__ ref,     // authority output
                 const int* __restrict__ idxs,
                 const int* __restrict__ map,
                 const float* __restrict__ zpage,
                 int* __restrict__ cnt,             // mismatch counter
                 int n)
{
    __shared__ int s_nbr[27 * VPB];
    __shared__ int s_lin[VPB];
    __shared__ int s_tyx[VPB];

    int tid = threadIdx.x;
    int lane = tid & 63;
    int wid = tid >> 6;
    int vox0 = blockIdx.x * VPB;

    if (tid < VPB) {
        int v = vox0 + tid;
        int4 q = *(const int4*)(idxs + 4 * (size_t)v);
        s_tyx[tid] = (q.y << 20) | (q.z << 10) | q.w;
        s_lin[tid] = ((q.x * 21 + q.y) * 400 + q.z) * 400 + q.w;
    }
    __syncthreads();

    for (int j = tid; j < 27 * VPB; j += 256) {
        int k = j >> 7;
        int v = j & (VPB - 1);
        int dt = k / 9 - 1;
        int rem = k % 9;
        int dy = rem / 3 - 1;
        int dx = rem % 3 - 1;
        int tyx = s_tyx[v];
        int t0 = tyx >> 20, y0 = (tyx >> 10) & 1023, x0 = tyx & 1023;
        int tt = t0 + dt, yy = y0 + dy, xx = x0 + dx;
        bool valid = ((unsigned)tt < 21u) & ((unsigned)yy < 400u)
                   & ((unsigned)xx < 400u);
        int key = s_lin[v] + dt * (SBB_H * SBB_W) + dy * SBB_W + dx;
        int lo = map[valid ? key : 0];
        s_nbr[j] = valid ? lo : -1;
    }
    __syncthreads();

    int m = lane & 15;
    int kg = lane >> 4;

    f32x4 c0[4], c1[4];
    #pragma unroll
    for (int nt = 0; nt < 4; ++nt) {
        c0[nt] = (f32x4){0.f, 0.f, 0.f, 0.f};
        c1[nt] = (f32x4){0.f, 0.f, 0.f, 0.f};
    }

    for (int k = 0; k < 27; ++k) {
        int n0 = s_nbr[(k << 7) + wid * 32 + m];
        int n1 = s_nbr[(k << 7) + wid * 32 + 16 + m];
        unsigned long long bal = __ballot(n0 >= 0) | __ballot(n1 >= 0);
        if (bal == 0ULL) continue;

        const float* base0 = (n0 >= 0) ? (A + (size_t)n0 * 64) : zpage;
        const float* base1 = (n1 >= 0) ? (A + (size_t)n1 * 64) : zpage;
        const unsigned short* wkh = whi + ((size_t)k << 12);
        const unsigned short* wkl = wlo + ((size_t)k << 12);

        #pragma unroll
        for (int h = 0; h < 2; ++h) {
            int cp = (h << 2) + kg;
            const float4* p0 = (const float4*)(base0 + cp * 8);
            float4 a0f0 = p0[0], a0f1 = p0[1];
            const float4* p1 = (const float4*)(base1 + cp * 8);
            float4 a1f0 = p1[0], a1f1 = p1[1];
            sbb_frag a0h, a0l, a1h, a1l;
            sbb_split8(a0f0, a0f1, a0h.u, a0l.u);
            sbb_split8(a1f0, a1f1, a1h.u, a1l.u);
            #pragma unroll
            for (int nt = 0; nt < 4; ++nt) {
                int off = ((nt * 16 + m) << 6) + (cp << 3);
                bf16x8 bh = *(const bf16x8*)(wkh + off);
                bf16x8 bl = *(const bf16x8*)(wkl + off);
                c0[nt] = __builtin_amdgcn_mfma_f32_16x16x32_bf16(a0h.v, bh, c0[nt], 0, 0, 0);
                c0[nt] = __builtin_amdgcn_mfma_f32_16x16x32_bf16(a0h.v, bl, c0[nt], 0, 0, 0);
                c0[nt] = __builtin_amdgcn_mfma_f32_16x16x32_bf16(a0l.v, bh, c0[nt], 0, 0, 0);
                c1[nt] = __builtin_amdgcn_mfma_f32_16x16x32_bf16(a1h.v, bh, c1[nt], 0, 0, 0);
                c1[nt] = __builtin_amdgcn_mfma_f32_16x16x32_bf16(a1h.v, bl, c1[nt], 0, 0, 0);
                c1[nt] = __builtin_amdgcn_mfma_f32_16x16x32_bf16(a1l.v, bh, c1[nt], 0, 0, 0);
            }
        }
    }

    float gm[4], bt[4];
    #pragma unroll
    for (int nt = 0; nt < 4; ++nt) {
        gm[nt] = gamma[nt * 16 + m];
        bt[nt] = beta[nt * 16 + m];
    }

    bool bad = false;
    #pragma unroll
    for (int tile = 0; tile < 2; ++tile) {
        f32x4* cc = tile ? c1 : c0;
        int vbase = vox0 + wid * 32 + tile * 16;
        #pragma unroll
        for (int r = 0; r < 4; ++r) {
            float e0 = cc[0][r], e1 = cc[1][r], e2 = cc[2][r], e3 = cc[3][r];
            float s = e0 + e1 + e2 + e3;
            float q = e0 * e0 + e1 * e1 + e2 * e2 + e3 * e3;
            #pragma unroll
            for (int msk = 1; msk <= 8; msk <<= 1) {
                s += __shfl_xor(s, msk, 64);
                q += __shfl_xor(q, msk, 64);
            }
            float mean = s * 0.015625f;
            float var = q * 0.015625f - mean * mean;
            var = var < 0.f ? 0.f : var;
            float rstd = rsqrtf(var + 1e-5f);

            int vv = vbase + kg * 4 + r;
            size_t ob = (size_t)vv * 64 + m;
            #pragma unroll
            for (int nt = 0; nt < 4; ++nt) {
                float e = (nt == 0) ? e0 : (nt == 1) ? e1 : (nt == 2) ? e2 : e3;
                float y = (e - mean) * rstd * gm[nt] + bt[nt];
                size_t oi = ob + nt * 16;
                if (USE_RES) y += residual[oi];
                if (y < 0.f) y = 0.f;
                if (fabsf(y - ref[oi]) > 0.05f) bad = true;   // compare, don't store
            }
        }
    }
    if (__any(bad) && lane == 0) atomicAdd(cnt, 1);
}

// ---- duration-encoded diagnosis (top-5-proof) ----
__global__ void sbb_diag9(const int* __restrict__ ctl, const int* __restrict__ cnt,
                          int* __restrict__ sink) {
    long long t = 0;
    if (ctl[0] == 0) t += 1800000;   // ~3 ms : calibration failed
    if (cnt[0] > 0)  t += 3600000;   // ~6 ms : conv1 shadow mismatch
    if (cnt[1] > 0)  t += 7200000;   // ~12 ms: conv2 shadow mismatch
    float x = 1.0f;
    for (long long i = 0; i < t; ++i) x = fmaf(x, 1.0000001f, 1e-7f);
    if (x == 12345.678f) sink[0] = 1;
}

// ---- round-1 kernel kept verbatim as the small-workspace fallback ----
__global__ void sbb_conv_old(
    const float* featsf, const unsigned short* featsb, const float* w,
    const float* gamma, const float* beta, const float* residual,
    float* outf, unsigned short* outb, const int* lin, const int* idxs,
    const int* map, int n, int use_residual, int feats_bf16, int out_bf16,
    int use_map)
{
    int tid = threadIdx.x;
    int vox = blockIdx.x * 4 + (tid >> 6);
    if (vox >= n) return;
    int co = tid & 63;

    int t0 = idxs[4 * vox + 1];
    int y0 = idxs[4 * vox + 2];
    int x0 = idxs[4 * vox + 3];
    int mylin = lin[vox];

    float acc = 0.0f;
    #pragma unroll
    for (int dt = -1; dt <= 1; ++dt) {
        int tt = t0 + dt;
        if (tt < 0 || tt >= SBB_T) continue;
        #pragma unroll
        for (int dy = -1; dy <= 1; ++dy) {
            int yy = y0 + dy;
            if (yy < 0 || yy >= SBB_H) continue;
            #pragma unroll
            for (int dx = -1; dx <= 1; ++dx) {
                int xx = x0 + dx;
                if (xx < 0 || xx >= SBB_W) continue;
                int key = mylin + dt * (SBB_H * SBB_W) + dy * SBB_W + dx;
                int lo;
                if (use_map) {
                    lo = map[key];
                } else {
                    int l = 0, h = n;
                    while (l < h) {
                        int mm2 = (l + h) >> 1;
                        if (lin[mm2] < key) l = mm2 + 1; else h = mm2;
                    }
                    lo = (l < n && lin[l] == key) ? l : -1;
                }
                if (lo < 0) continue;
                int kk = (dt + 1) * 9 + (dy + 1) * 3 + (dx + 1);
                const float* wr = w + kk * 4096 + co;
                if (feats_bf16) {
                    const unsigned short* fr = featsb + (size_t)lo * 64;
                    #pragma unroll 4
                    for (int c4 = 0; c4 < 16; ++c4) {
                        ushort4 fv = *(const ushort4*)(fr + c4 * 4);
                        const float* wp = wr + c4 * 256;
                        acc += sbb_b2f(fv.x) * wp[0];
                        acc += sbb_b2f(fv.y) * wp[64];
                        acc += sbb_b2f(fv.z) * wp[128];
                        acc += sbb_b2f(fv.w) * wp[192];
                    }
                } else {
                    const float4* fr = (const float4*)(featsf + (size_t)lo * 64);
                    #pragma unroll 4
                    for (int c4 = 0; c4 < 16; ++c4) {
                        float4 fv = fr[c4];
                        const float* wp = wr + c4 * 256;
                        acc += fv.x * wp[0];
                        acc += fv.y * wp[64];
                        acc += fv.z * wp[128];
                        acc += fv.w * wp[192];
                    }
                }
            }
        }
    }

    float s = acc, q = acc * acc;
    #pragma unroll
    for (int mm2 = 32; mm2 > 0; mm2 >>= 1) {
        s += __shfl_xor(s, mm2, 64);
        q += __shfl_xor(q, mm2, 64);
    }
    float mean = s * 0.015625f;
    float var = q * 0.015625f - mean * mean;
    if (var < 0.0f) var = 0.0f;
    float rstd = rsqrtf(var + 1e-5f);

    float yv = (acc - mean) * rstd * gamma[co] + beta[co];
    int oi = vox * 64 + co;
    if (use_residual) yv += residual[oi];
    if (yv < 0.0f) yv = 0.0f;
    if (out_bf16) {
        outb[oi] = sbb_f2b(yv);
    } else {
        outf[oi] = yv;
    }
}

extern "C" void kernel_launch(void* const* d_in, const int* in_sizes, int n_in,
                              void* d_out, int out_size, void* d_ws, size_t ws_size,
                              hipStream_t stream) {
    const float* feats = (const float*)d_in[0];
    const int* idxs = (const int*)d_in[1];
    const float* w1 = (const float*)d_in[2];
    const float* g1 = (const float*)d_in[3];
    const float* b1 = (const float*)d_in[4];
    const float* w2 = (const float*)d_in[5];
    const float* g2 = (const float*)d_in[6];
    const float* b2 = (const float*)d_in[7];
    float* out = (float*)d_out;

    int n = SBB_N;

    size_t map_b  = (size_t)SBB_TOTAL * 4;        // 26.88 MB
    size_t midf_b = (size_t)n * 64 * 4;           // 102.4 MB fp32 mid
    size_t wb_b   = (size_t)27 * 4096 * 2;        // 221184 B per bf16 hi/lo buffer
    size_t wtf_b  = (size_t)27 * 4096 * 4;        // 442368 B per fp32 W^T
    size_t zb_b   = 768;
    size_t lin_b  = (size_t)n * 4;                // fallback only
    size_t midb_b = (size_t)n * 64 * 2;           // fallback bf16 mid

    size_t need_new = map_b + midf_b + 4 * wb_b + 2 * wtf_b + zb_b; // ~131.05 MB
    size_t need_old = lin_b + map_b + midb_b;                       // 79.7 MB
    size_t need_min = lin_b + midb_b;                               // 52.8 MB

    if (ws_size >= need_new) {
        char* p = (char*)d_ws;
        int* map = (int*)p;                        p += map_b;
        float* mid = (float*)p;                    p += midf_b;
        unsigned short* wh1 = (unsigned short*)p;  p += wb_b;
        unsigned short* wl1 = (unsigned short*)p;  p += wb_b;
        unsigned short* wh2 = (unsigned short*)p;  p += wb_b;
        unsigned short* wl2 = (unsigned short*)p;  p += wb_b;
        float* wtf1 = (float*)p;                   p += wtf_b;
        float* wtf2 = (float*)p;                   p += wtf_b;
        float* zb = (float*)p;                     // [0..64) zeros
        int* ctl = (int*)((char*)zb + 256);        // [0]=ok, [1..32]=sigma
        int* cnt = (int*)((char*)zb + 512);        // [0]=c1,[1]=c2,[2]=sink

        sbb_fill_kernel<<<1, 256, 0, stream>>>(zb, 64, 0.0f);
        sbb_izero<<<1, 64, 0, stream>>>(cnt, 3);
        sbb_probe<<<1, 64, 0, stream>>>(mid);
        sbb_decode<<<1, 64, 0, stream>>>(mid, ctl);
        sbb_verify<<<1, 64, 0, stream>>>(ctl);
        sbb_wsplit<<<27, 256, 0, stream>>>(w1, wh1, wl1, ctl);
        sbb_wsplit<<<27, 256, 0, stream>>>(w2, wh2, wl2, ctl);
        sbb_wtf<<<27, 256, 0, stream>>>(w1, wtf1);
        sbb_wtf<<<27, 256, 0, stream>>>(w2, wtf2);
        sbb_map_init<<<(SBB_TOTAL + 255) / 256, 256, 0, stream>>>(map);
        sbb_map_set2<<<(n + 255) / 256, 256, 0, stream>>>(idxs, map, n);

        int grid_conv = n / VPB;                   // 3125
        // authority conv1 -> mid
        sbb_valu9<0><<<grid_conv, 256, 0, stream>>>(
            feats, wtf1, g1, b1, feats, mid, idxs, map, n);
        // shadow conv1: MFMA recompute vs mid -> cnt[0]
        sbb_shadow9<0><<<grid_conv, 256, 0, stream>>>(
            feats, wh1, wl1, g1, b1, feats, mid, idxs, map, zb, &cnt[0], n);
        // authority conv2 -> out
        sbb_valu9<1><<<grid_conv, 256, 0, stream>>>(
            mid, wtf2, g2, b2, feats, out, idxs, map, n);
        // shadow conv2: MFMA recompute (same input mid) vs out -> cnt[1]
        sbb_shadow9<1><<<grid_conv, 256, 0, stream>>>(
            mid, wh2, wl2, g2, b2, feats, out, idxs, map, zb, &cnt[1], n);
        // readout
        sbb_diag9<<<1, 64, 0, stream>>>(ctl, cnt, &cnt[2]);
        return;
    }

    if (ws_size < need_min) {
        sbb_fill_kernel<<<(n * 64 + 255) / 256, 256, 0, stream>>>(out, n * 64, 1000.0f);
        return;
    }

    // small-workspace fallback: proven round-1 path
    int use_map = (ws_size >= need_old) ? 1 : 0;
    int* lin = (int*)d_ws;
    int* map = nullptr;
    unsigned short* mid;
    if (use_map) {
        map = (int*)((char*)d_ws + lin_b);
        mid = (unsigned short*)((char*)d_ws + lin_b + map_b);
    } else {
        mid = (unsigned short*)((char*)d_ws + lin_b);
    }

    int grid_lin = (n + 255) / 256;
    sbb_lin_kernel<<<grid_lin, 256, 0, stream>>>(idxs, lin, n);
    if (use_map) {
        sbb_map_init<<<(SBB_TOTAL + 255) / 256, 256, 0, stream>>>(map);
        sbb_map_set<<<grid_lin, 256, 0, stream>>>(lin, map, n);
    }

    sbb_conv_old<<<n / 4, 256, 0, stream>>>(
        feats, (const unsigned short*)feats, w1, g1, b1, feats,
        (float*)mid, mid, lin, idxs, map, n, 0, 0, 1, use_map);
    sbb_conv_old<<<n / 4, 256, 0, stream>>>(
        feats, mid, w2, g2, b2, feats,
        out, (unsigned short*)out, lin, idxs, map, n, 1, 1, 0, use_map);
}